// Round 1
// baseline (3071.440 us; speedup 1.0000x reference)
//
#include <hip/hip_runtime.h>
#include <cstdint>
#include <cstddef>

// Problem: B=8, S=2048, D=H=1024, fp32.
//   x = x_batch @ lin_w^T + lin_b          (NT GEMM + bias)
//   Q = x@W_q; K = x@W_k; V = x@W_v        (NN GEMMs; K,V -> d_out cache slots)
//   S_b = Q_b @ K_b^T  (causal mask, NO 1/sqrt(d) scale)
//   F_b = softmax(S_b) @ V_b
// d_out layout: [F (16.78M) | K (16.78M) | V (16.78M)] floats.
// x is staged in the F region (dead before PV writes F).

#define TILE 64
#define KT 16
#define LDP (TILE + 4)   // +4 keeps LDS rows 16B-aligned for ds_read_b128; 2-way bank alias is free

// C[M,N] = A[M,K] @ op(B) (+bias). BT: B is [N,K] (dot of rows). CMASK: causal
// -inf mask on C (scores). CK: clip K-loop at row0+TILE (PV causal skip).
template<bool BT, bool BIAS, bool CMASK, bool CK>
__global__ __launch_bounds__(256)
void gemm_f32(const float* __restrict__ A, const float* __restrict__ B,
              const float* __restrict__ bias, float* __restrict__ C,
              int M, int N, int K, size_t sA, size_t sB, size_t sC)
{
    const int bm = blockIdx.y, bn = blockIdx.x;
    const int row0 = bm * TILE, col0 = bn * TILE;
    if (CMASK && col0 > row0 + (TILE - 1)) return;  // fully-masked block: never read downstream

    A += (size_t)blockIdx.z * sA;
    B += (size_t)blockIdx.z * sB;
    C += (size_t)blockIdx.z * sC;

    __shared__ float As[KT][LDP];   // [k][m]
    __shared__ float Bs[KT][LDP];   // [k][n]

    const int t  = threadIdx.x;
    const int tx = t & 15, ty = t >> 4;
    const int lm = t >> 2;          // 0..63
    const int lk = (t & 3) << 2;    // 0,4,8,12

    int kEnd = K;
    if (CK) kEnd = min(K, row0 + TILE);

    float acc[4][4] = {};

    for (int k0 = 0; k0 < kEnd; k0 += KT) {
        // A tile 64x16, stored transposed As[k][m]
        {
            float4 a = *(const float4*)(A + (size_t)(row0 + lm) * K + (k0 + lk));
            As[lk + 0][lm] = a.x; As[lk + 1][lm] = a.y;
            As[lk + 2][lm] = a.z; As[lk + 3][lm] = a.w;
        }
        if (BT) {
            float4 b = *(const float4*)(B + (size_t)(col0 + lm) * K + (k0 + lk));
            Bs[lk + 0][lm] = b.x; Bs[lk + 1][lm] = b.y;
            Bs[lk + 2][lm] = b.z; Bs[lk + 3][lm] = b.w;
        } else {
            const int bk  = t >> 4;         // 0..15
            const int bn4 = (t & 15) << 2;  // 0..60
            *(float4*)&Bs[bk][bn4] =
                *(const float4*)(B + (size_t)(k0 + bk) * N + (col0 + bn4));
        }
        __syncthreads();
        #pragma unroll
        for (int kk = 0; kk < KT; ++kk) {
            float av[4], bv[4];
            *(float4*)av = *(const float4*)&As[kk][ty << 2];
            *(float4*)bv = *(const float4*)&Bs[kk][tx << 2];
            #pragma unroll
            for (int i = 0; i < 4; ++i)
                #pragma unroll
                for (int j = 0; j < 4; ++j)
                    acc[i][j] = fmaf(av[i], bv[j], acc[i][j]);
        }
        __syncthreads();
    }

    #pragma unroll
    for (int i = 0; i < 4; ++i) {
        const int r = row0 + (ty << 2) + i;
        float4 o;
        float* po = &o.x;
        #pragma unroll
        for (int j = 0; j < 4; ++j) {
            const int c = col0 + (tx << 2) + j;
            float v = acc[i][j];
            if (BIAS) v += bias[c];
            if (CMASK && c > r) v = -__builtin_huge_valf();
            po[j] = v;
        }
        *(float4*)(C + (size_t)r * N + col0 + (tx << 2)) = o;
    }
}

// Row softmax over causal scores. Row q only has valid data in [0, kend) with
// kend = round64(q+1) (exactly the region the score GEMM wrote; entries past q
// are -inf -> exp 0, which PV then reads as zeros).
__global__ __launch_bounds__(256)
void softmax_causal(float* __restrict__ Sc, size_t batchStride, int ncols)
{
    const int q = blockIdx.x;
    float* row = Sc + (size_t)blockIdx.y * batchStride + (size_t)q * ncols;
    const int kend = (q & ~63) + 64;
    const int t = threadIdx.x;
    __shared__ float red[4];

    float m = -__builtin_huge_valf();
    for (int k = t; k < kend; k += 256) m = fmaxf(m, row[k]);
    #pragma unroll
    for (int off = 32; off; off >>= 1) m = fmaxf(m, __shfl_down(m, off, 64));
    if ((t & 63) == 0) red[t >> 6] = m;
    __syncthreads();
    m = fmaxf(fmaxf(red[0], red[1]), fmaxf(red[2], red[3]));
    __syncthreads();

    float e[8];  // kend <= 2048 -> <= 8 per thread
    float s = 0.f;
    int i = 0;
    for (int k = t; k < kend; k += 256, ++i) {
        float v = __expf(row[k] - m);
        e[i] = v;
        s += v;
    }
    #pragma unroll
    for (int off = 32; off; off >>= 1) s += __shfl_down(s, off, 64);
    if ((t & 63) == 0) red[t >> 6] = s;
    __syncthreads();
    s = red[0] + red[1] + red[2] + red[3];
    const float inv = 1.0f / s;
    i = 0;
    for (int k = t; k < kend; k += 256, ++i) row[k] = e[i] * inv;
}

extern "C" void kernel_launch(void* const* d_in, const int* in_sizes, int n_in,
                              void* d_out, int out_size, void* d_ws, size_t ws_size,
                              hipStream_t stream)
{
    const float* x_batch = (const float*)d_in[0];
    const float* lin_w   = (const float*)d_in[1];
    const float* lin_b   = (const float*)d_in[2];
    const float* W_q     = (const float*)d_in[3];
    const float* W_k     = (const float*)d_in[4];
    const float* W_v     = (const float*)d_in[5];

    constexpr int Bn = 8, S = 2048, D = 1024;
    constexpr size_t MS = (size_t)Bn * S;     // 16384 rows
    constexpr size_t NE = MS * (size_t)D;     // 16,777,216 elems per tensor

    float* out = (float*)d_out;
    float* Fo = out;            // F
    float* Kc = out + NE;       // cache[0] = K
    float* Vc = out + 2 * NE;   // cache[1] = V

    float* x  = Fo;             // stage x in F region (dead before PV writes F)
    float* Q  = (float*)d_ws;   // 64 MB
    float* Sc = Q + NE;         // scores after Q

    const dim3 blk(256);
    const dim3 gBig(D / TILE, MS / TILE, 1);   // 16 x 256

    // x = x_batch @ lin_w^T + lin_b
    gemm_f32<true, true, false, false><<<gBig, blk, 0, stream>>>(
        x_batch, lin_w, lin_b, x, (int)MS, D, D, 0, 0, 0);
    // Q, K, V
    gemm_f32<false, false, false, false><<<gBig, blk, 0, stream>>>(
        x, W_q, nullptr, Q, (int)MS, D, D, 0, 0, 0);
    gemm_f32<false, false, false, false><<<gBig, blk, 0, stream>>>(
        x, W_k, nullptr, Kc, (int)MS, D, D, 0, 0, 0);
    gemm_f32<false, false, false, false><<<gBig, blk, 0, stream>>>(
        x, W_v, nullptr, Vc, (int)MS, D, D, 0, 0, 0);

    const size_t scorePer = (size_t)S * S;     // 4.19M floats = 16 MB
    const size_t strideQKV = (size_t)S * D;
    const bool batched = ws_size >= (NE + (size_t)Bn * scorePer) * sizeof(float);

    if (batched) {
        // all 8 batches concurrently, scores strided in ws
        gemm_f32<true, false, true, false><<<dim3(S / TILE, S / TILE, Bn), blk, 0, stream>>>(
            Q, Kc, nullptr, Sc, S, S, D, strideQKV, strideQKV, scorePer);
        softmax_causal<<<dim3(S, Bn, 1), blk, 0, stream>>>(Sc, scorePer, S);
        gemm_f32<false, false, false, true><<<dim3(D / TILE, S / TILE, Bn), blk, 0, stream>>>(
            Sc, Vc, nullptr, Fo, S, D, S, scorePer, strideQKV, strideQKV);
    } else {
        // sequential per batch, one 16 MB score buffer (needs 80 MB ws total)
        for (int b = 0; b < Bn; ++b) {
            const float* Qb = Q  + (size_t)b * strideQKV;
            const float* Kb = Kc + (size_t)b * strideQKV;
            const float* Vb = Vc + (size_t)b * strideQKV;
            float*       Fb = Fo + (size_t)b * strideQKV;
            gemm_f32<true, false, true, false><<<dim3(S / TILE, S / TILE, 1), blk, 0, stream>>>(
                Qb, Kb, nullptr, Sc, S, S, D, 0, 0, 0);
            softmax_causal<<<dim3(S, 1, 1), blk, 0, stream>>>(Sc, 0, S);
            gemm_f32<false, false, false, true><<<dim3(D / TILE, S / TILE, 1), blk, 0, stream>>>(
                Sc, Vb, nullptr, Fb, S, D, S, 0, 0, 0);
        }
    }
}

// Round 3
// 1903.257 us; speedup vs baseline: 1.6138x; 1.6138x over previous
//
#include <hip/hip_runtime.h>
#include <cstdint>
#include <cstddef>

// B=8, S=2048, D=H=1024, fp32 in/out.
// Pipeline (all GEMMs on bf16 MFMA 16x16x32, fp32 accumulate):
//   split(x_batch), split(lin_w), splitT(W_q), splitT(W_k), splitT_h(W_v)
//   x   = xb @ lin_w^T + b      [SPLIT 3-pass, out: bf16 hi/lo -> F region]
//   Q,K = x @ W                 [SPLIT, out: hi/lo pairs (+K fp32 cache)]
//   V   = x_h @ W_v_h           [single pass, fp32 cache; then transpose->V_hT bf16]
//   S_b = Q_b K_b^T (causal)    [SPLIT, fp32 scores]  -- logits need ~1e-2 accuracy
//   P_b = softmax(S_b) -> bf16
//   F_b = P_b @ V_b             [single pass]
// ws (proven >= 201.3 MB by round-1 dispatch pattern): Qpair|Kpair|V_hT|X
// X region reused: weights (14 MB, dead after V GEMM) then S+P (24 MB).
// x_batch pair staged in K-cache region (dead before K GEMM writes).
// x pair staged in F region (dead before PV writes F).

typedef short bf16x8 __attribute__((ext_vector_type(8)));
typedef float f32x4 __attribute__((ext_vector_type(4)));

__device__ __forceinline__ unsigned short f2bf(float f) {
    unsigned u = __float_as_uint(f);
    return (unsigned short)((u + 0x7fffu + ((u >> 16) & 1u)) >> 16);
}
__device__ __forceinline__ float bf2f(unsigned short h) {
    return __uint_as_float(((unsigned)h) << 16);
}

#define GLDS(gp, lp)                                                                \
    __builtin_amdgcn_global_load_lds((const __attribute__((address_space(1))) void*)(gp), \
                                     (__attribute__((address_space(3))) void*)(lp), 16, 0, 0)

// ---------------- conversion kernels ----------------

__global__ __launch_bounds__(256)
void cvt_split(const float* __restrict__ in, unsigned short* __restrict__ h,
               unsigned short* __restrict__ l, size_t n4)
{
    size_t i = (size_t)blockIdx.x * blockDim.x + threadIdx.x;
    size_t stride = (size_t)gridDim.x * blockDim.x;
    for (; i < n4; i += stride) {
        float4 v = ((const float4*)in)[i];
        unsigned short h0 = f2bf(v.x), h1 = f2bf(v.y), h2 = f2bf(v.z), h3 = f2bf(v.w);
        uint2 hp, lp;
        hp.x = (unsigned)h0 | ((unsigned)h1 << 16);
        hp.y = (unsigned)h2 | ((unsigned)h3 << 16);
        lp.x = (unsigned)f2bf(v.x - bf2f(h0)) | ((unsigned)f2bf(v.y - bf2f(h1)) << 16);
        lp.y = (unsigned)f2bf(v.z - bf2f(h2)) | ((unsigned)f2bf(v.w - bf2f(h3)) << 16);
        ((uint2*)h)[i] = hp;
        ((uint2*)l)[i] = lp;
    }
}

// out[c][r] = in[r][c], fp32 -> bf16 hi (+lo). Coalesced both sides via LDS tile.
template<bool PAIR>
__global__ __launch_bounds__(256)
void cvt_split_T(const float* __restrict__ in, unsigned short* __restrict__ hT,
                 unsigned short* __restrict__ lT, int R, int C,
                 size_t inBatch, size_t outBatch)
{
    __shared__ float tile[64][65];
    in += (size_t)blockIdx.z * inBatch;
    hT += (size_t)blockIdx.z * outBatch;
    const int c0 = blockIdx.x * 64, r0 = blockIdx.y * 64;
    const int tx = threadIdx.x & 63, ty = threadIdx.x >> 6;
    for (int i = ty; i < 64; i += 4)
        tile[i][tx] = in[(size_t)(r0 + i) * C + c0 + tx];
    __syncthreads();
    for (int i = ty; i < 64; i += 4) {
        float v = tile[tx][i];
        unsigned short hh = f2bf(v);
        size_t off = (size_t)(c0 + i) * R + r0 + tx;
        hT[off] = hh;
        if (PAIR) (lT + (size_t)blockIdx.z * outBatch)[off] = f2bf(v - bf2f(hh));
    }
}

// ---------------- MFMA GEMM, BT layout everywhere ----------------
// C[M,N] = (Ah+Al)[M,K] @ (Bh+Bl)[N,K]^T.  128x128 block, BK=32, 4 waves (2x2 of 64x64).
// LDS is fragment-contiguous: chunk c (1 KB) holds rows [16c,16c+16) x 32k in MFMA
// lane order, so global_load_lds (base + lane*16) writes it directly and
// ds_read_b128 at (chunk, lane*16) is conflict-free.

template<bool SPLIT, bool BIAS, bool CMASK, bool CK, bool OUTF, bool OUTH, bool OUTL>
__global__ __launch_bounds__(256)
void gemm_bf16(const unsigned short* __restrict__ Ah, const unsigned short* __restrict__ Al,
               const unsigned short* __restrict__ Bh, const unsigned short* __restrict__ Bl,
               const float* __restrict__ bias,
               float* __restrict__ C, unsigned short* __restrict__ Ch,
               unsigned short* __restrict__ Cl,
               int K, int ldA, int ldB, int ldC)
{
    const int row0 = blockIdx.y * 128, col0 = blockIdx.x * 128;
    if (CMASK && col0 > row0 + 127) return;

    extern __shared__ __align__(16) unsigned short sm[];
    unsigned short* sAh = sm;            // 4096 ushorts (8 KB)
    unsigned short* sBh = sm + 4096;
    unsigned short* sAl = sm + 8192;     // only touched when SPLIT
    unsigned short* sBl = sm + 12288;

    const int t = threadIdx.x;
    const int wave = t >> 6, lane = t & 63;
    const int wr = wave >> 1, wc = wave & 1;
    const int mrow = lane & 15, kg = lane >> 4;

    int kEnd = K;
    if (CK) kEnd = min(K, row0 + 128);

    f32x4 acc[4][4] = {};

    const int c0 = wave * 2, c1 = wave * 2 + 1;
    const size_t aOff0 = (size_t)(row0 + c0 * 16 + mrow) * ldA + kg * 8;
    const size_t aOff1 = (size_t)(row0 + c1 * 16 + mrow) * ldA + kg * 8;
    const size_t bOff0 = (size_t)(col0 + c0 * 16 + mrow) * ldB + kg * 8;
    const size_t bOff1 = (size_t)(col0 + c1 * 16 + mrow) * ldB + kg * 8;

    for (int k0 = 0; k0 < kEnd; k0 += 32) {
        GLDS(Ah + aOff0 + k0, sAh + c0 * 512);
        GLDS(Ah + aOff1 + k0, sAh + c1 * 512);
        GLDS(Bh + bOff0 + k0, sBh + c0 * 512);
        GLDS(Bh + bOff1 + k0, sBh + c1 * 512);
        if (SPLIT) {
            GLDS(Al + aOff0 + k0, sAl + c0 * 512);
            GLDS(Al + aOff1 + k0, sAl + c1 * 512);
            GLDS(Bl + bOff0 + k0, sBl + c0 * 512);
            GLDS(Bl + bOff1 + k0, sBl + c1 * 512);
        }
        __syncthreads();   // compiler drains vmcnt before barrier

        bf16x8 afh[4], bfh[4], afl[4], bfl[4];
        #pragma unroll
        for (int i = 0; i < 4; ++i) {
            afh[i] = *(const bf16x8*)(sAh + (wr * 4 + i) * 512 + lane * 8);
            bfh[i] = *(const bf16x8*)(sBh + (wc * 4 + i) * 512 + lane * 8);
            if (SPLIT) {
                afl[i] = *(const bf16x8*)(sAl + (wr * 4 + i) * 512 + lane * 8);
                bfl[i] = *(const bf16x8*)(sBl + (wc * 4 + i) * 512 + lane * 8);
            }
        }
        #pragma unroll
        for (int i = 0; i < 4; ++i)
            #pragma unroll
            for (int j = 0; j < 4; ++j) {
                acc[i][j] = __builtin_amdgcn_mfma_f32_16x16x32_bf16(afh[i], bfh[j], acc[i][j], 0, 0, 0);
                if (SPLIT) {
                    acc[i][j] = __builtin_amdgcn_mfma_f32_16x16x32_bf16(afh[i], bfl[j], acc[i][j], 0, 0, 0);
                    acc[i][j] = __builtin_amdgcn_mfma_f32_16x16x32_bf16(afl[i], bfh[j], acc[i][j], 0, 0, 0);
                }
            }
        __syncthreads();
    }

    // epilogue: C/D layout col=lane&15, row=(lane>>4)*4+reg (m89-verified)
    const int rb = (lane >> 4) * 4;
    const int cl = lane & 15;
    #pragma unroll
    for (int j = 0; j < 4; ++j) {
        const int col = col0 + wc * 64 + j * 16 + cl;
        float bv = BIAS ? bias[col] : 0.f;
        #pragma unroll
        for (int i = 0; i < 4; ++i) {
            const int rw = row0 + wr * 64 + i * 16 + rb;
            #pragma unroll
            for (int r = 0; r < 4; ++r) {
                const int row = rw + r;
                float v = acc[i][j][r];
                if (BIAS) v += bv;
                if (CMASK && col > row) v = -__builtin_huge_valf();
                const size_t off = (size_t)row * ldC + col;
                if (OUTF) C[off] = v;
                if (OUTH) {
                    unsigned short hh = f2bf(v);
                    Ch[off] = hh;
                    if (OUTL) Cl[off] = f2bf(v - bf2f(hh));
                }
            }
        }
    }
}

// ---------------- softmax: fp32 scores -> bf16 probabilities ----------------
// Row q valid in [0, kend128); masked entries are -inf -> exp 0 (PV's CK clip
// reads exactly [0, round128(q+1)), so zeros there are required and provided).
__global__ __launch_bounds__(256)
void softmax_p(const float* __restrict__ S, unsigned short* __restrict__ P, int ncols)
{
    const int q = blockIdx.x;
    const float* row = S + (size_t)q * ncols;
    unsigned short* prow = P + (size_t)q * ncols;
    const int kend = (q & ~127) + 128;
    const int t = threadIdx.x;
    __shared__ float red[4];

    float m = -__builtin_huge_valf();
    for (int k = t; k < kend; k += 256) m = fmaxf(m, row[k]);
    #pragma unroll
    for (int off = 32; off; off >>= 1) m = fmaxf(m, __shfl_down(m, off, 64));
    if ((t & 63) == 0) red[t >> 6] = m;
    __syncthreads();
    m = fmaxf(fmaxf(red[0], red[1]), fmaxf(red[2], red[3]));
    __syncthreads();

    float e[8];
    float s = 0.f;
    int i = 0;
    for (int k = t; k < kend; k += 256, ++i) {
        float v = __expf(row[k] - m);
        e[i] = v;
        s += v;
    }
    #pragma unroll
    for (int off = 32; off; off >>= 1) s += __shfl_down(s, off, 64);
    if ((t & 63) == 0) red[t >> 6] = s;
    __syncthreads();
    s = red[0] + red[1] + red[2] + red[3];
    const float inv = 1.0f / s;
    i = 0;
    for (int k = t; k < kend; k += 256, ++i) prow[k] = f2bf(e[i] * inv);
}

// ---------------- fp32 fallback (round-1 kernels), used only if ws too small ----
#define TILE 64
#define KT 16
#define LDP (TILE + 4)
template<bool BT, bool BIAS, bool CMASK, bool CK>
__global__ __launch_bounds__(256)
void gemm_f32(const float* __restrict__ A, const float* __restrict__ B,
              const float* __restrict__ bias, float* __restrict__ C,
              int M, int N, int K, size_t sA, size_t sB, size_t sC)
{
    const int bm = blockIdx.y, bn = blockIdx.x;
    const int row0 = bm * TILE, col0 = bn * TILE;
    if (CMASK && col0 > row0 + (TILE - 1)) return;
    A += (size_t)blockIdx.z * sA; B += (size_t)blockIdx.z * sB; C += (size_t)blockIdx.z * sC;
    __shared__ float As[KT][LDP];
    __shared__ float Bs[KT][LDP];
    const int t = threadIdx.x;
    const int tx = t & 15, ty = t >> 4;
    const int lm = t >> 2, lk = (t & 3) << 2;
    int kEnd = K;
    if (CK) kEnd = min(K, row0 + TILE);
    float acc[4][4] = {};
    for (int k0 = 0; k0 < kEnd; k0 += KT) {
        {
            float4 a = *(const float4*)(A + (size_t)(row0 + lm) * K + (k0 + lk));
            As[lk + 0][lm] = a.x; As[lk + 1][lm] = a.y; As[lk + 2][lm] = a.z; As[lk + 3][lm] = a.w;
        }
        if (BT) {
            float4 b = *(const float4*)(B + (size_t)(col0 + lm) * K + (k0 + lk));
            Bs[lk + 0][lm] = b.x; Bs[lk + 1][lm] = b.y; Bs[lk + 2][lm] = b.z; Bs[lk + 3][lm] = b.w;
        } else {
            const int bk = t >> 4, bn4 = (t & 15) << 2;
            *(float4*)&Bs[bk][bn4] = *(const float4*)(B + (size_t)(k0 + bk) * N + (col0 + bn4));
        }
        __syncthreads();
        #pragma unroll
        for (int kk = 0; kk < KT; ++kk) {
            float av[4], bv[4];
            *(float4*)av = *(const float4*)&As[kk][ty << 2];
            *(float4*)bv = *(const float4*)&Bs[kk][tx << 2];
            #pragma unroll
            for (int i = 0; i < 4; ++i)
                #pragma unroll
                for (int j = 0; j < 4; ++j) acc[i][j] = fmaf(av[i], bv[j], acc[i][j]);
        }
        __syncthreads();
    }
    #pragma unroll
    for (int i = 0; i < 4; ++i) {
        const int r = row0 + (ty << 2) + i;
        float4 o; float* po = &o.x;
        #pragma unroll
        for (int j = 0; j < 4; ++j) {
            const int c = col0 + (tx << 2) + j;
            float v = acc[i][j];
            if (BIAS) v += bias[c];
            if (CMASK && c > r) v = -__builtin_huge_valf();
            po[j] = v;
        }
        *(float4*)(C + (size_t)r * N + col0 + (tx << 2)) = o;
    }
}
__global__ __launch_bounds__(256)
void softmax_causal(float* __restrict__ Sc, size_t batchStride, int ncols)
{
    const int q = blockIdx.x;
    float* row = Sc + (size_t)blockIdx.y * batchStride + (size_t)q * ncols;
    const int kend = (q & ~63) + 64;
    const int t = threadIdx.x;
    __shared__ float red[4];
    float m = -__builtin_huge_valf();
    for (int k = t; k < kend; k += 256) m = fmaxf(m, row[k]);
    #pragma unroll
    for (int off = 32; off; off >>= 1) m = fmaxf(m, __shfl_down(m, off, 64));
    if ((t & 63) == 0) red[t >> 6] = m;
    __syncthreads();
    m = fmaxf(fmaxf(red[0], red[1]), fmaxf(red[2], red[3]));
    __syncthreads();
    float e[8]; float s = 0.f; int i = 0;
    for (int k = t; k < kend; k += 256, ++i) { float v = __expf(row[k] - m); e[i] = v; s += v; }
    #pragma unroll
    for (int off = 32; off; off >>= 1) s += __shfl_down(s, off, 64);
    if ((t & 63) == 0) red[t >> 6] = s;
    __syncthreads();
    s = red[0] + red[1] + red[2] + red[3];
    const float inv = 1.0f / s;
    i = 0;
    for (int k = t; k < kend; k += 256, ++i) row[k] = e[i] * inv;
}

// ---------------- launch ----------------

extern "C" void kernel_launch(void* const* d_in, const int* in_sizes, int n_in,
                              void* d_out, int out_size, void* d_ws, size_t ws_size,
                              hipStream_t stream)
{
    const float* x_batch = (const float*)d_in[0];
    const float* lin_w   = (const float*)d_in[1];
    const float* lin_b   = (const float*)d_in[2];
    const float* W_q     = (const float*)d_in[3];
    const float* W_k     = (const float*)d_in[4];
    const float* W_v     = (const float*)d_in[5];

    constexpr int Bn = 8, S = 2048, D = 1024;
    constexpr size_t MS = (size_t)Bn * S;          // 16384
    constexpr size_t NE = MS * (size_t)D;          // 16,777,216
    constexpr size_t SB = (size_t)S * D;           // per-batch QKV stride

    float* out = (float*)d_out;
    float* Fo = out;
    float* Kc = out + NE;
    float* Vc = out + 2 * NE;

    // ws layout (bytes): Qh|Ql|Kh|Kl|V_hT|X
    const size_t needFast = NE * 2 * 2ull      // Q pair
                          + NE * 2 * 2ull      // K pair
                          + NE * 2ull          // V_hT
                          + 25165824ull;       // X = max(weights 14.0 MB, S 16 MB + P 8 MB)

    if (ws_size >= needFast) {
        unsigned short* Qh  = (unsigned short*)d_ws;
        unsigned short* Ql  = Qh + NE;
        unsigned short* Kh  = Ql + NE;
        unsigned short* Kl  = Kh + NE;
        unsigned short* VhT = Kl + NE;
        unsigned short* X   = VhT + NE;        // reused region
        unsigned short* lwh = X,            *lwl = X + 1048576;
        unsigned short* wqh = X + 2097152,  *wql = X + 3145728;
        unsigned short* wkh = X + 4194304,  *wkl = X + 5242880;
        unsigned short* wvh = X + 6291456;
        float*          Sc  = (float*)X;                       // 2048*2048 fp32
        unsigned short* Ph  = (unsigned short*)(Sc + (size_t)S * S);

        // staging in d_out dead regions
        unsigned short* xbh = (unsigned short*)Kc;   // K region dead until K GEMM
        unsigned short* xbl = xbh + NE;
        unsigned short* xh  = (unsigned short*)Fo;   // F region dead until PV
        unsigned short* xl  = xh + NE;

        const dim3 blk(256);

        // 1. conversions
        cvt_split<<<4096, blk, 0, stream>>>(x_batch, xbh, xbl, NE / 4);
        cvt_split<<<512,  blk, 0, stream>>>(lin_w, lwh, lwl, (size_t)D * D / 4);
        cvt_split_T<true ><<<dim3(16, 16, 1), blk, 0, stream>>>(W_q, wqh, wql, D, D, 0, 0);
        cvt_split_T<true ><<<dim3(16, 16, 1), blk, 0, stream>>>(W_k, wkh, wkl, D, D, 0, 0);
        cvt_split_T<false><<<dim3(16, 16, 1), blk, 0, stream>>>(W_v, wvh, nullptr, D, D, 0, 0);

        const dim3 gBig(D / 128, MS / 128);  // 8 x 128

        // 2. x = xb @ lin_w^T + b   (SPLIT, BIAS, out pair)
        gemm_bf16<true, true, false, false, false, true, true>
            <<<gBig, blk, 32768, stream>>>(xbh, xbl, lwh, lwl, lin_b,
                                           nullptr, xh, xl, D, D, D, D);
        // 3. Q = x @ W_q  (SPLIT, out pair)
        gemm_bf16<true, false, false, false, false, true, true>
            <<<gBig, blk, 32768, stream>>>(xh, xl, wqh, wql, nullptr,
                                           nullptr, Qh, Ql, D, D, D, D);
        // 4. K = x @ W_k  (SPLIT, out fp32 cache + pair)
        gemm_bf16<true, false, false, false, true, true, true>
            <<<gBig, blk, 32768, stream>>>(xh, xl, wkh, wkl, nullptr,
                                           Kc, Kh, Kl, D, D, D, D);
        // 5. V = x_h @ W_v_h  (single pass, fp32 cache)
        gemm_bf16<false, false, false, false, true, false, false>
            <<<gBig, blk, 16384, stream>>>(xh, nullptr, wvh, nullptr, nullptr,
                                           Vc, nullptr, nullptr, D, D, D, D);
        // 6. V_hT[b][h][s] = bf16(V[b][s][h])
        cvt_split_T<false><<<dim3(D / 64, S / 64, Bn), blk, 0, stream>>>(
            Vc, VhT, nullptr, S, D, SB, SB);

        // 7. attention, per batch
        for (int b = 0; b < Bn; ++b) {
            const size_t o = (size_t)b * SB;
            gemm_bf16<true, false, true, false, true, false, false>
                <<<dim3(S / 128, S / 128), blk, 32768, stream>>>(
                    Qh + o, Ql + o, Kh + o, Kl + o, nullptr,
                    Sc, nullptr, nullptr, D, D, D, S);
            softmax_p<<<S, blk, 0, stream>>>(Sc, Ph, S);
            gemm_bf16<false, false, false, true, true, false, false>
                <<<dim3(D / 128, S / 128), blk, 16384, stream>>>(
                    Ph, nullptr, VhT + o, nullptr, nullptr,
                    Fo + o, nullptr, nullptr, S, S, S, D);
        }
    } else {
        // fp32 fallback (round-1 structure)
        float* x  = Fo;
        float* Q  = (float*)d_ws;
        float* Sc = Q + NE;
        const dim3 blk(256);
        const dim3 gBig(D / TILE, MS / TILE, 1);
        gemm_f32<true, true, false, false><<<gBig, blk, 0, stream>>>(
            x_batch, lin_w, lin_b, x, (int)MS, D, D, 0, 0, 0);
        gemm_f32<false, false, false, false><<<gBig, blk, 0, stream>>>(
            x, W_q, nullptr, Q, (int)MS, D, D, 0, 0, 0);
        gemm_f32<false, false, false, false><<<gBig, blk, 0, stream>>>(
            x, W_k, nullptr, Kc, (int)MS, D, D, 0, 0, 0);
        gemm_f32<false, false, false, false><<<gBig, blk, 0, stream>>>(
            x, W_v, nullptr, Vc, (int)MS, D, D, 0, 0, 0);
        for (int b = 0; b < Bn; ++b) {
            const float* Qb = Q  + (size_t)b * SB;
            const float* Kb = Kc + (size_t)b * SB;
            const float* Vb = Vc + (size_t)b * SB;
            float*       Fb = Fo + (size_t)b * SB;
            gemm_f32<true, false, true, false><<<dim3(S / TILE, S / TILE, 1), blk, 0, stream>>>(
                Qb, Kb, nullptr, Sc, S, S, D, 0, 0, 0);
            softmax_causal<<<dim3(S, 1, 1), blk, 0, stream>>>(Sc, 0, S);
            gemm_f32<false, false, false, true><<<dim3(D / TILE, S / TILE, 1), blk, 0, stream>>>(
                Sc, Vb, nullptr, Fb, S, D, S, 0, 0, 0);
        }
    }
}